// Round 3
// baseline (1672.529 us; speedup 1.0000x reference)
//
#include <hip/hip_runtime.h>

// ---------------------------------------------------------------------------
// Two stacked SwinV2 shifted-window attentions, MI355X/gfx950.
// v3: occupancy-first. X kept in global as bf16 (NHWC); k_swin has NO X/O
// staging LDS -> 36.9 KB LDS -> 4 blocks/CU (was 2). QKV/proj GEMM A-operands
// and the block-local AO tile are read straight from global (L2-hot).
// Pipeline: t_in (NCHW f32 -> NHWC bf16) -> k_swin(pass1: residual from NCHW
// src, writes X1 f32 + X1 bf16) -> k_swin(pass2: in-place on X1) -> t_out.
// Mask is folded into a doubled cpb bias table (second half = bias - 100).
// ---------------------------------------------------------------------------

typedef short bf16x8 __attribute__((ext_vector_type(8)));
typedef float f32x4 __attribute__((ext_vector_type(4)));

__device__ __forceinline__ unsigned short f2bf(float f) {
    union { float f; unsigned int u; } v; v.f = f;
    return (unsigned short)((v.u + 0x7fffu + ((v.u >> 16) & 1u)) >> 16);
}
__device__ __forceinline__ float bf2f(unsigned short b) {
    union { unsigned int u; float f; } v; v.u = ((unsigned int)b) << 16;
    return v.f;
}
__device__ __forceinline__ f32x4 mfma_bf16(bf16x8 a, bf16x8 b, f32x4 c) {
    return __builtin_amdgcn_mfma_f32_16x16x32_bf16(a, b, c, 0, 0, 0);
}

// region id for the swin shifted mask (pH=pW=64, ws=8, shift=4).
__device__ __forceinline__ int region_of(int wh, int ww, int t) {
    int th = t >> 3, tw = t & 7;
    int rh = (wh == 7) ? ((th < 4) ? 1 : 2) : 0;
    int rw = (ww == 7) ? ((tw < 4) ? 1 : 2) : 0;
    return rh * 3 + rw;
}

// ---------------------------------------------------------------------------
// setup: blocks 0..511 convert weights f32->bf16; blocks 512/513 compute the
// cpb tables through 16*sigmoid, duplicated with -100 (mask fold): [2][225][8].
// ---------------------------------------------------------------------------
__global__ __launch_bounds__(256) void k_setup(
    const float* __restrict__ qkvw1, const float* __restrict__ projw1,
    const float* __restrict__ qkvw2, const float* __restrict__ projw2,
    const float* __restrict__ w1a, const float* __restrict__ b1a, const float* __restrict__ w2a,
    const float* __restrict__ w1b, const float* __restrict__ b1b, const float* __restrict__ w2b,
    unsigned short* __restrict__ qw1, unsigned short* __restrict__ pw1,
    unsigned short* __restrict__ qw2, unsigned short* __restrict__ pw2,
    float* __restrict__ bt1, float* __restrict__ bt2)
{
    int b = blockIdx.x, t = threadIdx.x;
    if (b < 512) {
        int idx = b * 256 + t;
        #pragma unroll
        for (int r = 0; r < 4; r++) {
            int i = idx + r * 131072;
            if (i < 196608)        qw1[i]          = f2bf(qkvw1[i]);
            else if (i < 262144)   pw1[i - 196608] = f2bf(projw1[i - 196608]);
            else if (i < 458752)   qw2[i - 262144] = f2bf(qkvw2[i - 262144]);
            else                   pw2[i - 458752] = f2bf(projw2[i - 458752]);
        }
    } else {
        int a = b - 512;
        const float* w1 = a ? w1b : w1a;
        const float* b1 = a ? b1b : b1a;
        const float* w2 = a ? w2b : w2a;
        float* out = a ? bt2 : bt1;
        int k = t;
        if (k >= 225) return;
        int ih = k / 15, iw = k % 15;
        float v0 = (float)(ih - 7) / 7.0f * 8.0f;
        float v1 = (float)(iw - 7) / 7.0f * 8.0f;
        float t0 = (v0 >= 0.f ? 1.f : -1.f) * log2f(fabsf(v0) + 1.f) / 3.0f;
        float t1 = (v1 >= 0.f ? 1.f : -1.f) * log2f(fabsf(v1) + 1.f) / 3.0f;
        float acc[8] = {0.f, 0.f, 0.f, 0.f, 0.f, 0.f, 0.f, 0.f};
        for (int c = 0; c < 512; c++) {
            float hc = t0 * w1[2 * c] + t1 * w1[2 * c + 1] + b1[c];
            hc = fmaxf(hc, 0.f);
            #pragma unroll
            for (int h = 0; h < 8; h++) acc[h] += hc * w2[h * 512 + c];
        }
        #pragma unroll
        for (int h = 0; h < 8; h++) {
            float s = 16.f / (1.f + expf(-acc[h]));
            out[k * 8 + h] = s;            // unmasked half
            out[1800 + k * 8 + h] = s - 100.f;  // masked half
        }
    }
}

// ---------------------------------------------------------------------------
// t_in: NCHW f32 [32][256][4096] -> NHWC bf16 [32][4096][256]
// 128(hw) x 32(c) tiles, float4 loads, ushort4 stores.
// ---------------------------------------------------------------------------
__global__ __launch_bounds__(256) void t_in(const float* __restrict__ src, unsigned short* __restrict__ dst) {
    __shared__ float tile[32][132];
    int img = blockIdx.z, hw0 = blockIdx.x * 128, c0 = blockIdx.y * 32;
    int tid = threadIdx.x;
    #pragma unroll
    for (int k = 0; k < 4; k++) {
        int cl = (tid >> 5) + k * 8;
        int hw4 = (tid & 31) * 4;
        float4 v = *(const float4*)(src + ((size_t)img * 256 + c0 + cl) * 4096 + hw0 + hw4);
        *(float4*)&tile[cl][hw4] = v;
    }
    __syncthreads();
    #pragma unroll
    for (int j = 0; j < 4; j++) {
        int hwl = (tid >> 3) + j * 32;
        int c4 = (tid & 7) * 4;
        ushort4 o;
        o.x = f2bf(tile[c4 + 0][hwl]); o.y = f2bf(tile[c4 + 1][hwl]);
        o.z = f2bf(tile[c4 + 2][hwl]); o.w = f2bf(tile[c4 + 3][hwl]);
        *(ushort4*)(dst + ((size_t)img * 4096 + hw0 + hwl) * 256 + c0 + c4) = o;
    }
}

// t_out: NHWC f32 [32][4096][256] -> NCHW f32 [32][256][4096]
__global__ __launch_bounds__(256) void t_out(const float* __restrict__ src, float* __restrict__ dst) {
    __shared__ float tile[32][132];
    int img = blockIdx.z, hw0 = blockIdx.x * 128, c0 = blockIdx.y * 32;
    int tid = threadIdx.x;
    #pragma unroll
    for (int j = 0; j < 4; j++) {
        int hwl = (tid >> 3) + j * 32;
        int c4 = (tid & 7) * 4;
        float4 v = *(const float4*)(src + ((size_t)img * 4096 + hw0 + hwl) * 256 + c0 + c4);
        tile[c4 + 0][hwl] = v.x; tile[c4 + 1][hwl] = v.y;
        tile[c4 + 2][hwl] = v.z; tile[c4 + 3][hwl] = v.w;
    }
    __syncthreads();
    #pragma unroll
    for (int k = 0; k < 4; k++) {
        int cl = (tid >> 5) + k * 8;
        int hw4 = (tid & 31) * 4;
        float4 o = *(const float4*)&tile[cl][hw4];
        *(float4*)(dst + ((size_t)img * 256 + c0 + cl) * 4096 + hw0 + hw4) = o;
    }
}

// ---------------------------------------------------------------------------
// k_swin: one block per window (2048 blocks, 256 thr = 4 waves, 4 blocks/CU).
// Phase A (x4 head-pairs): QKV GEMM (A from global bf16 X, B = Wq) ->
//   epilogue writes q/k to sQKV + V transposed to sVt -> barrier ->
//   norm phase (sInv) -> barrier -> 2 heads: S=Qn Kn^T*scale+bias(table holds
//   mask fold) -> softmax -> PV -> AO (global, block-local) -> barrier.
// Phase B: proj GEMM (A = own AO tile from global/L2, B = Wp) + bias +
//   residual (NCHW src for pass 1, NHWC f32 for pass 2) -> Xout (+bf16 copy).
// ---------------------------------------------------------------------------
__global__ __launch_bounds__(256, 4) void k_swin(
    const float* Xres,                       // residual: NCHW src (pass1) or NHWC f32 (pass2)
    const unsigned short* __restrict__ X16,  // NHWC bf16 [32][4096][256] (GEMM A input)
    const unsigned short* __restrict__ Wq,   // qkv_w bf16 [768][256]
    const float* __restrict__ bq,            // qkv_b f32 [768]
    const float* __restrict__ lsc,           // logit_scale [8]
    const float* __restrict__ btab,          // 16*sigmoid bias [2][225][8] (2nd half -100)
    const unsigned short* __restrict__ Wp,   // proj_w bf16 [256][256]
    const float* __restrict__ bp,            // proj_b [256]
    unsigned short* __restrict__ AO,         // attn_out bf16 [2048][64][256] (scratch)
    float* Xout,                             // output NHWC f32 (may alias Xres in pass 2)
    unsigned short* __restrict__ Xout16,     // optional bf16 copy of output (pass 1)
    int shift, int masked, int res_nchw)
{
    __shared__ __align__(16) unsigned short sQKV[64 * 136];  // q0|q1|k0|k1 (32 chans each)
    __shared__ __align__(16) unsigned short sP[64 * 72];     // softmax probs bf16
    __shared__ __align__(16) unsigned short sVt[64 * 72];    // V transposed [dim][token]
    __shared__ float sInv[256];                              // 1/norm: q0,q1,k0,k1

    const int tid = threadIdx.x;
    const int wv = tid >> 6, lane = tid & 63, quad = lane >> 4, nn = lane & 15;
    const int win = blockIdx.x;
    const int bt = win >> 6, wh = (win >> 3) & 7, ww = win & 7;
    const f32x4 zero4 = {0.f, 0.f, 0.f, 0.f};

    // per-thread A-row bases (shift roll folded); row = token rt*16+nn
    size_t abase[4];
    #pragma unroll
    for (int rt = 0; rt < 4; rt++) {
        int tok = rt * 16 + nn;
        int h = (wh * 8 + (tok >> 3) + shift) & 63;
        int w = (ww * 8 + (tok & 7) + shift) & 63;
        abase[rt] = ((size_t)(bt * 4096 + h * 64 + w)) * 256;
    }

    // rel-bias table offsets; mask folded by selecting the -100 table half
    int reloff[4][4];
    #pragma unroll
    for (int ct = 0; ct < 4; ct++) {
        int j = ct * 16 + nn;
        int rj = region_of(wh, ww, j);
        #pragma unroll
        for (int r = 0; r < 4; r++) {
            int i = wv * 16 + quad * 4 + r;
            int rel = ((i >> 3) - (j >> 3) + 7) * 15 + ((i & 7) - (j & 7) + 7);
            bool mk = masked && (region_of(wh, ww, i) != rj);
            reloff[ct][r] = rel * 8 + (mk ? 1800 : 0);
        }
    }

    // ======================= Phase A: attention =======================
    for (int p = 0; p < 4; p++) {
        // ===== QKV GEMM: 12 wave-disjoint col-tiles (q0 q1 k0 k1 v0 v1) =====
        f32x4 acc[4][3];
        #pragma unroll
        for (int rt = 0; rt < 4; rt++)
            #pragma unroll
            for (int c = 0; c < 3; c++) acc[rt][c] = zero4;

        int wrow[3], secv[3], colb[3];
        #pragma unroll
        for (int c = 0; c < 3; c++) {
            int ct = wv * 3 + c;           // 12 col-tiles
            int sec = ct >> 1;             // 0..5 : q0 q1 k0 k1 v0 v1
            int kind = sec >> 1;           // 0=q 1=k 2=v
            int head = 2 * p + (sec & 1);
            wrow[c] = kind * 256 + head * 32 + (ct & 1) * 16 + nn;
            secv[c] = sec;
            colb[c] = (sec < 4) ? (sec * 32 + (ct & 1) * 16 + nn)
                                : ((sec - 4) * 32 + (ct & 1) * 16 + nn);
        }
        #pragma unroll
        for (int ks = 0; ks < 8; ks++) {
            bf16x8 a[4], b[3];
            #pragma unroll
            for (int rt = 0; rt < 4; rt++)
                a[rt] = *(const bf16x8*)(X16 + abase[rt] + ks * 32 + quad * 8);
            #pragma unroll
            for (int c = 0; c < 3; c++)
                b[c] = *(const bf16x8*)(Wq + (size_t)wrow[c] * 256 + ks * 32 + quad * 8);
            #pragma unroll
            for (int rt = 0; rt < 4; rt++)
                #pragma unroll
                for (int c = 0; c < 3; c++)
                    acc[rt][c] = mfma_bf16(a[rt], b[c], acc[rt][c]);
        }

        // ===== epilogue: q/k -> sQKV; v -> sVt (transposed) =====
        #pragma unroll
        for (int c = 0; c < 3; c++) {
            int sec = secv[c];
            if (sec < 4) {
                float bias = (sec >= 2) ? 0.f : bq[wrow[c]];  // v2 zeroes key bias
                int col = colb[c];
                #pragma unroll
                for (int rt = 0; rt < 4; rt++)
                    #pragma unroll
                    for (int r = 0; r < 4; r++)
                        sQKV[(rt * 16 + quad * 4 + r) * 136 + col] = f2bf(acc[rt][c][r] + bias);
            } else {
                float bv = bq[wrow[c]];
                int vchan = colb[c];
                #pragma unroll
                for (int rt = 0; rt < 4; rt++)
                    #pragma unroll
                    for (int r = 0; r < 4; r++)
                        sVt[vchan * 72 + rt * 16 + quad * 4 + r] = f2bf(acc[rt][c][r] + bv);
            }
        }
        __syncthreads();

        // ===== norm phase: sInv for q0,q1,k0,k1 (b128 reads) =====
        {
            int t = tid & 63, sec = tid >> 6;
            const unsigned short* row = sQKV + t * 136 + sec * 32;
            float ss = 0.f;
            #pragma unroll
            for (int j = 0; j < 4; j++) {
                bf16x8 v = *(const bf16x8*)(row + j * 8);
                #pragma unroll
                for (int i = 0; i < 8; i++) {
                    float f = bf2f((unsigned short)v[i]);
                    ss += f * f;
                }
            }
            sInv[sec * 64 + t] = 1.f / fmaxf(sqrtf(ss), 1e-12f);
        }
        __syncthreads();

        #pragma unroll
        for (int hh = 0; hh < 2; hh++) {
            const int head = 2 * p + hh;
            const float scale = __expf(fminf(lsc[head], 4.605170185988092f)); // ln(100)

            // ----- S = Q K^T (wave wv owns rows wv*16..wv*16+15) -----
            bf16x8 aq = *(const bf16x8*)(sQKV + (wv * 16 + nn) * 136 + hh * 32 + quad * 8);
            f32x4 S[4];
            #pragma unroll
            for (int ct = 0; ct < 4; ct++) {
                bf16x8 bk = *(const bf16x8*)(sQKV + (ct * 16 + nn) * 136 + 64 + hh * 32 + quad * 8);
                S[ct] = mfma_bf16(aq, bk, zero4);
            }

            const int i_base = wv * 16 + quad * 4;
            float iq[4];
            #pragma unroll
            for (int r = 0; r < 4; r++) iq[r] = sInv[hh * 64 + i_base + r];

            float rowm[4] = {-3.0e38f, -3.0e38f, -3.0e38f, -3.0e38f};
            #pragma unroll
            for (int ct = 0; ct < 4; ct++) {
                int j = ct * 16 + nn;
                float ivk = sInv[(2 + hh) * 64 + j];
                #pragma unroll
                for (int r = 0; r < 4; r++) {
                    float v = S[ct][r] * iq[r] * ivk * scale + btab[reloff[ct][r] + head];
                    S[ct][r] = v;
                    rowm[r] = fmaxf(rowm[r], v);
                }
            }
            #pragma unroll
            for (int r = 0; r < 4; r++) {
                float m = rowm[r];
                m = fmaxf(m, __shfl_xor(m, 1));
                m = fmaxf(m, __shfl_xor(m, 2));
                m = fmaxf(m, __shfl_xor(m, 4));
                m = fmaxf(m, __shfl_xor(m, 8));
                rowm[r] = m;
            }
            float rsum[4] = {0.f, 0.f, 0.f, 0.f};
            #pragma unroll
            for (int ct = 0; ct < 4; ct++)
                #pragma unroll
                for (int r = 0; r < 4; r++) {
                    float e = __expf(S[ct][r] - rowm[r]);
                    S[ct][r] = e;
                    rsum[r] += e;
                }
            #pragma unroll
            for (int r = 0; r < 4; r++) {
                float s = rsum[r];
                s += __shfl_xor(s, 1);
                s += __shfl_xor(s, 2);
                s += __shfl_xor(s, 4);
                s += __shfl_xor(s, 8);
                rsum[r] = 1.f / s;
            }
            // write P (wave-private rows -> no barrier needed before PV)
            #pragma unroll
            for (int ct = 0; ct < 4; ct++)
                #pragma unroll
                for (int r = 0; r < 4; r++)
                    sP[(i_base + r) * 72 + ct * 16 + nn] = f2bf(S[ct][r] * rsum[r]);

            // ----- O = P V  (K=64 -> 2 ksteps; 2 col tiles of 16 dims) -----
            bf16x8 ap0 = *(const bf16x8*)(sP + (wv * 16 + nn) * 72 + quad * 8);
            bf16x8 ap1 = *(const bf16x8*)(sP + (wv * 16 + nn) * 72 + 32 + quad * 8);
            #pragma unroll
            for (int ct2 = 0; ct2 < 2; ct2++) {
                bf16x8 bv0 = *(const bf16x8*)(sVt + (hh * 32 + ct2 * 16 + nn) * 72 + quad * 8);
                bf16x8 bv1 = *(const bf16x8*)(sVt + (hh * 32 + ct2 * 16 + nn) * 72 + 32 + quad * 8);
                f32x4 O = mfma_bf16(ap0, bv0, zero4);
                O = mfma_bf16(ap1, bv1, O);
                #pragma unroll
                for (int r = 0; r < 4; r++) {
                    int tokr = i_base + r;
                    AO[((size_t)win * 64 + tokr) * 256 + head * 32 + ct2 * 16 + nn] = f2bf(O[r]);
                }
            }
        }
        __syncthreads();  // protect sQKV/sVt/sInv; drains AO stores (vmcnt(0))
    }

    // ======================= Phase B: projection =======================
    // A-operand: this block's own AO tile, straight from global (L2-hot).
    f32x4 pacc[4][4];
    #pragma unroll
    for (int rt = 0; rt < 4; rt++)
        #pragma unroll
        for (int c = 0; c < 4; c++) pacc[rt][c] = zero4;

    int prow[4];
    #pragma unroll
    for (int c = 0; c < 4; c++) prow[c] = (wv * 4 + c) * 16 + nn;  // output channel

    #pragma unroll
    for (int ks = 0; ks < 8; ks++) {
        bf16x8 a[4], b[4];
        #pragma unroll
        for (int rt = 0; rt < 4; rt++)
            a[rt] = *(const bf16x8*)(AO + ((size_t)win * 64 + rt * 16 + nn) * 256 + ks * 32 + quad * 8);
        #pragma unroll
        for (int c = 0; c < 4; c++)
            b[c] = *(const bf16x8*)(Wp + (size_t)prow[c] * 256 + ks * 32 + quad * 8);
        #pragma unroll
        for (int rt = 0; rt < 4; rt++)
            #pragma unroll
            for (int c = 0; c < 4; c++)
                pacc[rt][c] = mfma_bf16(a[rt], b[c], pacc[rt][c]);
    }

    #pragma unroll
    for (int c = 0; c < 4; c++) {
        int chan = prow[c];
        float bias = bp[chan];
        #pragma unroll
        for (int rt = 0; rt < 4; rt++)
            #pragma unroll
            for (int r = 0; r < 4; r++) {
                int tok = rt * 16 + quad * 4 + r;
                int h = (wh * 8 + (tok >> 3) + shift) & 63;
                int w = (ww * 8 + (tok & 7) + shift) & 63;
                size_t idx = ((size_t)(bt * 4096 + h * 64 + w)) * 256 + chan;
                float res = res_nchw ? Xres[((size_t)(bt * 256 + chan)) * 4096 + h * 64 + w]
                                     : Xres[idx];
                float o = pacc[rt][c][r] + bias + res;
                Xout[idx] = o;
                if (Xout16) Xout16[idx] = f2bf(o);
            }
    }
}

// ---------------------------------------------------------------------------
extern "C" void kernel_launch(void* const* d_in, const int* in_sizes, int n_in,
                              void* d_out, int out_size, void* d_ws, size_t ws_size,
                              hipStream_t stream) {
    (void)in_sizes; (void)n_in; (void)out_size; (void)ws_size;

    const float* src        = (const float*)d_in[0];
    const float* a1_qkv_w   = (const float*)d_in[1];
    const float* a1_qkv_b   = (const float*)d_in[2];
    const float* a1_proj_w  = (const float*)d_in[3];
    const float* a1_proj_b  = (const float*)d_in[4];
    const float* a1_ls      = (const float*)d_in[5];
    const float* a1_w1      = (const float*)d_in[6];
    const float* a1_b1      = (const float*)d_in[7];
    const float* a1_w2      = (const float*)d_in[8];
    const float* a2_qkv_w   = (const float*)d_in[9];
    const float* a2_qkv_b   = (const float*)d_in[10];
    const float* a2_proj_w  = (const float*)d_in[11];
    const float* a2_proj_b  = (const float*)d_in[12];
    const float* a2_ls      = (const float*)d_in[13];
    const float* a2_w1      = (const float*)d_in[14];
    const float* a2_b1      = (const float*)d_in[15];
    const float* a2_w2      = (const float*)d_in[16];

    char* ws = (char*)d_ws;
    float* X1           = (float*)(ws);                         // 134217728 B (NHWC f32)
    unsigned short* X0b = (unsigned short*)(ws + 134217728);    //  67108864 B (NHWC bf16)
    unsigned short* X1b = (unsigned short*)(ws + 201326592);    //  67108864 B
    unsigned short* AO  = (unsigned short*)(ws + 268435456);    //  67108864 B
    unsigned short* qw1 = (unsigned short*)(ws + 335544320);
    unsigned short* qw2 = qw1 + 196608;
    unsigned short* pw1 = qw2 + 196608;
    unsigned short* pw2 = pw1 + 65536;
    float* bt1 = (float*)(pw2 + 65536);
    float* bt2 = bt1 + 3600;

    k_setup<<<514, 256, 0, stream>>>(a1_qkv_w, a1_proj_w, a2_qkv_w, a2_proj_w,
                                     a1_w1, a1_b1, a1_w2, a2_w1, a2_b1, a2_w2,
                                     qw1, pw1, qw2, pw2, bt1, bt2);
    t_in<<<dim3(32, 8, 32), 256, 0, stream>>>(src, X0b);

    // pass 1: no shift, no mask; residual from NCHW src; emits X1 f32 + bf16
    k_swin<<<2048, 256, 0, stream>>>(src, X0b, qw1, a1_qkv_b, a1_ls, bt1,
                                     pw1, a1_proj_b, AO, X1, X1b, 0, 0, 1);
    // pass 2: shift 4, masked; residual X1 (NHWC); in-place update of X1
    k_swin<<<2048, 256, 0, stream>>>(X1, X1b, qw2, a2_qkv_b, a2_ls, bt2,
                                     pw2, a2_proj_b, AO, X1, (unsigned short*)nullptr, 4, 1, 0);

    t_out<<<dim3(32, 8, 32), 256, 0, stream>>>(X1, (float*)d_out);
}

// Round 6
// 911.061 us; speedup vs baseline: 1.8358x; 1.8358x over previous
//
#include <hip/hip_runtime.h>

// ---------------------------------------------------------------------------
// Two stacked SwinV2 shifted-window attentions, MI355X/gfx950.
// v4 = R1 structure (X staged in LDS, window-local everything) with the proj
// fused INCREMENTALLY into the head-pair loop: head pair p emits O-slice
// (K-chans 64p..64p+63) into LDS, proj accumulates pacc += O_slice @ Wp-slice.
// No AO global buffer, no separate proj phase, no vmcnt-drain of O stores.
// Pipeline: t_in (NCHW->NHWC f32) -> k_swin x2 (pass2 in-place) -> t_out.
// Mask folded into doubled cpb table (2nd half = bias - 100).
// ---------------------------------------------------------------------------

typedef short bf16x8 __attribute__((ext_vector_type(8)));
typedef float f32x4 __attribute__((ext_vector_type(4)));

__device__ __forceinline__ unsigned short f2bf(float f) {
    union { float f; unsigned int u; } v; v.f = f;
    return (unsigned short)((v.u + 0x7fffu + ((v.u >> 16) & 1u)) >> 16);
}
__device__ __forceinline__ float bf2f(unsigned short b) {
    union { unsigned int u; float f; } v; v.u = ((unsigned int)b) << 16;
    return v.f;
}
__device__ __forceinline__ f32x4 mfma_bf16(bf16x8 a, bf16x8 b, f32x4 c) {
    return __builtin_amdgcn_mfma_f32_16x16x32_bf16(a, b, c, 0, 0, 0);
}

// region id for the swin shifted mask (pH=pW=64, ws=8, shift=4).
__device__ __forceinline__ int region_of(int wh, int ww, int t) {
    int th = t >> 3, tw = t & 7;
    int rh = (wh == 7) ? ((th < 4) ? 1 : 2) : 0;
    int rw = (ww == 7) ? ((tw < 4) ? 1 : 2) : 0;
    return rh * 3 + rw;
}

// ---------------------------------------------------------------------------
// setup: blocks 0..511 convert weights f32->bf16; blocks 512/513 compute the
// cpb tables through 16*sigmoid, duplicated with -100 (mask fold): [2][225][8].
// ---------------------------------------------------------------------------
__global__ __launch_bounds__(256) void k_setup(
    const float* __restrict__ qkvw1, const float* __restrict__ projw1,
    const float* __restrict__ qkvw2, const float* __restrict__ projw2,
    const float* __restrict__ w1a, const float* __restrict__ b1a, const float* __restrict__ w2a,
    const float* __restrict__ w1b, const float* __restrict__ b1b, const float* __restrict__ w2b,
    unsigned short* __restrict__ qw1, unsigned short* __restrict__ pw1,
    unsigned short* __restrict__ qw2, unsigned short* __restrict__ pw2,
    float* __restrict__ bt1, float* __restrict__ bt2)
{
    int b = blockIdx.x, t = threadIdx.x;
    if (b < 512) {
        int idx = b * 256 + t;
        #pragma unroll
        for (int r = 0; r < 4; r++) {
            int i = idx + r * 131072;
            if (i < 196608)        qw1[i]          = f2bf(qkvw1[i]);
            else if (i < 262144)   pw1[i - 196608] = f2bf(projw1[i - 196608]);
            else if (i < 458752)   qw2[i - 262144] = f2bf(qkvw2[i - 262144]);
            else                   pw2[i - 458752] = f2bf(projw2[i - 458752]);
        }
    } else {
        int a = b - 512;
        const float* w1 = a ? w1b : w1a;
        const float* b1 = a ? b1b : b1a;
        const float* w2 = a ? w2b : w2a;
        float* out = a ? bt2 : bt1;
        int k = t;
        if (k >= 225) return;
        int ih = k / 15, iw = k % 15;
        float v0 = (float)(ih - 7) / 7.0f * 8.0f;
        float v1 = (float)(iw - 7) / 7.0f * 8.0f;
        float t0 = (v0 >= 0.f ? 1.f : -1.f) * log2f(fabsf(v0) + 1.f) / 3.0f;
        float t1 = (v1 >= 0.f ? 1.f : -1.f) * log2f(fabsf(v1) + 1.f) / 3.0f;
        float acc[8] = {0.f, 0.f, 0.f, 0.f, 0.f, 0.f, 0.f, 0.f};
        for (int c = 0; c < 512; c++) {
            float hc = t0 * w1[2 * c] + t1 * w1[2 * c + 1] + b1[c];
            hc = fmaxf(hc, 0.f);
            #pragma unroll
            for (int h = 0; h < 8; h++) acc[h] += hc * w2[h * 512 + c];
        }
        #pragma unroll
        for (int h = 0; h < 8; h++) {
            float s = 16.f / (1.f + expf(-acc[h]));
            out[k * 8 + h] = s;                  // unmasked half
            out[1800 + k * 8 + h] = s - 100.f;   // masked half
        }
    }
}

// ---------------------------------------------------------------------------
// transposes: src [32][256][4096] <-> NHWC [32][4096][256], float4 both sides.
// ---------------------------------------------------------------------------
__global__ __launch_bounds__(256) void t_in(const float* __restrict__ src, float* __restrict__ dst) {
    __shared__ float tile[32][132];
    int img = blockIdx.z, hw0 = blockIdx.x * 128, c0 = blockIdx.y * 32;
    int tid = threadIdx.x;
    #pragma unroll
    for (int k = 0; k < 4; k++) {
        int cl = (tid >> 5) + k * 8;
        int hw4 = (tid & 31) * 4;
        float4 v = *(const float4*)(src + ((size_t)img * 256 + c0 + cl) * 4096 + hw0 + hw4);
        *(float4*)&tile[cl][hw4] = v;
    }
    __syncthreads();
    #pragma unroll
    for (int j = 0; j < 4; j++) {
        int hwl = (tid >> 3) + j * 32;
        int c4 = (tid & 7) * 4;
        float4 o;
        o.x = tile[c4 + 0][hwl]; o.y = tile[c4 + 1][hwl];
        o.z = tile[c4 + 2][hwl]; o.w = tile[c4 + 3][hwl];
        *(float4*)(dst + ((size_t)img * 4096 + hw0 + hwl) * 256 + c0 + c4) = o;
    }
}

__global__ __launch_bounds__(256) void t_out(const float* __restrict__ src, float* __restrict__ dst) {
    __shared__ float tile[32][132];
    int img = blockIdx.z, hw0 = blockIdx.x * 128, c0 = blockIdx.y * 32;
    int tid = threadIdx.x;
    #pragma unroll
    for (int j = 0; j < 4; j++) {
        int hwl = (tid >> 3) + j * 32;
        int c4 = (tid & 7) * 4;
        float4 v = *(const float4*)(src + ((size_t)img * 4096 + hw0 + hwl) * 256 + c0 + c4);
        tile[c4 + 0][hwl] = v.x; tile[c4 + 1][hwl] = v.y;
        tile[c4 + 2][hwl] = v.z; tile[c4 + 3][hwl] = v.w;
    }
    __syncthreads();
    #pragma unroll
    for (int k = 0; k < 4; k++) {
        int cl = (tid >> 5) + k * 8;
        int hw4 = (tid & 31) * 4;
        float4 o = *(const float4*)&tile[cl][hw4];
        *(float4*)(dst + ((size_t)img * 256 + c0 + cl) * 4096 + hw0 + hw4) = o;
    }
}

// ---------------------------------------------------------------------------
// k_swin: one block per window (2048 blocks, 256 thr = 4 waves, 2 blocks/CU).
// Per head-pair p (x4):
//   QKV GEMM (A from sX, B=Wq, 12 wave-disjoint col-tiles) -> epilogue:
//   q/k -> sQKV, V -> sVt (packed transposed) -> barrier -> norm (b128) ->
//   barrier -> 2 heads: S=QnKn^T*scale+bias(table has mask fold) -> softmax
//   -> PV -> O-slice into sO (LDS) -> barrier -> proj partial GEMM
//   (pacc += sO @ Wp[:,64p:64p+64]^T) -> barrier.
// End: out = pacc + bp + residual -> Xout NHWC f32 (roll-back folded).
// ---------------------------------------------------------------------------
__global__ __launch_bounds__(256, 2) void k_swin(
    const float* Xin,                        // NHWC f32 (staging source AND residual)
    const unsigned short* __restrict__ Wq,   // qkv_w bf16 [768][256]
    const float* __restrict__ bq,            // qkv_b f32 [768]
    const float* __restrict__ lsc,           // logit_scale [8]
    const float* __restrict__ btab,          // 16*sigmoid bias [2][225][8]
    const unsigned short* __restrict__ Wp,   // proj_w bf16 [256][256]
    const float* __restrict__ bp,            // proj_b [256]
    float* Xout,                             // output NHWC f32 (== Xin in pass 2)
    int shift, int masked)
{
    __shared__ __align__(16) unsigned short sX[64 * 264];    // X window bf16
    __shared__ __align__(16) unsigned short sQKV[64 * 136];  // q0|q1|k0|k1 (32 chans each)
    __shared__ __align__(16) unsigned short sP[64 * 72];     // softmax probs bf16
    __shared__ __align__(16) unsigned short sVt[64 * 72];    // V transposed [dim][token]
    __shared__ __align__(16) unsigned short sO[64 * 72];     // O-slice [token][64 chans]
    __shared__ float sInv[256];                              // 1/norm: q0,q1,k0,k1

    const int tid = threadIdx.x;
    const int wv = tid >> 6, lane = tid & 63, quad = lane >> 4, nn = lane & 15;
    const int win = blockIdx.x;
    const int bt = win >> 6, wh = (win >> 3) & 7, ww = win & 7;
    const f32x4 zero4 = {0.f, 0.f, 0.f, 0.f};

    // ---- stage X window (shift roll folded into the gather) ----
    {
        int tok = tid >> 2, part = tid & 3;
        int h = (wh * 8 + (tok >> 3) + shift) & 63;
        int w = (ww * 8 + (tok & 7) + shift) & 63;
        const float* srcp = Xin + ((size_t)(bt * 4096 + h * 64 + w)) * 256 + part * 64;
        unsigned short* dstp = sX + tok * 264 + part * 64;
        #pragma unroll
        for (int c = 0; c < 64; c += 8) {
            float4 v0 = *(const float4*)(srcp + c);
            float4 v1 = *(const float4*)(srcp + c + 4);
            uint4 o;
            o.x = (unsigned int)f2bf(v0.x) | ((unsigned int)f2bf(v0.y) << 16);
            o.y = (unsigned int)f2bf(v0.z) | ((unsigned int)f2bf(v0.w) << 16);
            o.z = (unsigned int)f2bf(v1.x) | ((unsigned int)f2bf(v1.y) << 16);
            o.w = (unsigned int)f2bf(v1.z) | ((unsigned int)f2bf(v1.w) << 16);
            *(uint4*)(dstp + c) = o;
        }
    }

    // rel-bias table offsets; mask folded by selecting the -100 table half
    int reloff[4][4];
    #pragma unroll
    for (int ct = 0; ct < 4; ct++) {
        int j = ct * 16 + nn;
        int rj = region_of(wh, ww, j);
        #pragma unroll
        for (int r = 0; r < 4; r++) {
            int i = wv * 16 + quad * 4 + r;
            int rel = ((i >> 3) - (j >> 3) + 7) * 15 + ((i & 7) - (j & 7) + 7);
            bool mk = masked && (region_of(wh, ww, i) != rj);
            reloff[ct][r] = rel * 8 + (mk ? 1800 : 0);
        }
    }

    int prow[4];
    #pragma unroll
    for (int c = 0; c < 4; c++) prow[c] = (wv * 4 + c) * 16 + nn;  // proj output channel

    f32x4 pacc[4][4];   // proj accumulator, persists across head pairs
    #pragma unroll
    for (int rt = 0; rt < 4; rt++)
        #pragma unroll
        for (int c = 0; c < 4; c++) pacc[rt][c] = zero4;

    __syncthreads();

    for (int p = 0; p < 4; p++) {
        // ===== QKV GEMM: 12 wave-disjoint col-tiles (q0 q1 k0 k1 v0 v1) =====
        f32x4 acc[4][3];
        #pragma unroll
        for (int rt = 0; rt < 4; rt++)
            #pragma unroll
            for (int c = 0; c < 3; c++) acc[rt][c] = zero4;

        int wrow[3], secv[3], colb[3];
        #pragma unroll
        for (int c = 0; c < 3; c++) {
            int ct = wv * 3 + c;           // 12 col-tiles
            int sec = ct >> 1;             // 0..5 : q0 q1 k0 k1 v0 v1
            int kind = sec >> 1;           // 0=q 1=k 2=v
            int head = 2 * p + (sec & 1);
            wrow[c] = kind * 256 + head * 32 + (ct & 1) * 16 + nn;
            secv[c] = sec;
            colb[c] = (sec < 4) ? (sec * 32 + (ct & 1) * 16 + nn)         // sQKV col
                                : ((sec - 4) * 32 + (ct & 1) * 16 + nn);  // sVt chan
        }
        #pragma unroll
        for (int ks = 0; ks < 8; ks++) {
            bf16x8 a[4], b[3];
            #pragma unroll
            for (int rt = 0; rt < 4; rt++)
                a[rt] = *(const bf16x8*)(sX + (rt * 16 + nn) * 264 + ks * 32 + quad * 8);
            #pragma unroll
            for (int c = 0; c < 3; c++)
                b[c] = *(const bf16x8*)(Wq + (size_t)wrow[c] * 256 + ks * 32 + quad * 8);
            #pragma unroll
            for (int rt = 0; rt < 4; rt++)
                #pragma unroll
                for (int c = 0; c < 3; c++)
                    acc[rt][c] = mfma_bf16(a[rt], b[c], acc[rt][c]);
        }

        // ===== epilogue: q/k -> sQKV; v -> sVt (packed transposed) =====
        #pragma unroll
        for (int c = 0; c < 3; c++) {
            int sec = secv[c];
            if (sec < 4) {
                float bias = (sec >= 2) ? 0.f : bq[wrow[c]];  // v2 zeroes key bias
                int col = colb[c];
                #pragma unroll
                for (int rt = 0; rt < 4; rt++)
                    #pragma unroll
                    for (int r = 0; r < 4; r++)
                        sQKV[(rt * 16 + quad * 4 + r) * 136 + col] = f2bf(acc[rt][c][r] + bias);
            } else {
                float bv = bq[wrow[c]];
                int vchan = colb[c];
                #pragma unroll
                for (int rt = 0; rt < 4; rt++) {
                    ushort4 pk;
                    pk.x = f2bf(acc[rt][c][0] + bv);
                    pk.y = f2bf(acc[rt][c][1] + bv);
                    pk.z = f2bf(acc[rt][c][2] + bv);
                    pk.w = f2bf(acc[rt][c][3] + bv);
                    *(ushort4*)(sVt + vchan * 72 + rt * 16 + quad * 4) = pk;
                }
            }
        }
        __syncthreads();

        // ===== norm phase: sInv for q0,q1,k0,k1 (b128 reads) =====
        {
            int t = tid & 63, sec = tid >> 6;
            const unsigned short* row = sQKV + t * 136 + sec * 32;
            float ss = 0.f;
            #pragma unroll
            for (int j = 0; j < 4; j++) {
                bf16x8 v = *(const bf16x8*)(row + j * 8);
                #pragma unroll
                for (int i = 0; i < 8; i++) {
                    float f = bf2f((unsigned short)v[i]);
                    ss += f * f;
                }
            }
            sInv[sec * 64 + t] = 1.f / fmaxf(sqrtf(ss), 1e-12f);
        }
        __syncthreads();

        #pragma unroll
        for (int hh = 0; hh < 2; hh++) {
            const int head = 2 * p + hh;
            const float scale = __expf(fminf(lsc[head], 4.605170185988092f)); // ln(100)

            // ----- S = Q K^T (wave wv owns rows wv*16..wv*16+15) -----
            bf16x8 aq = *(const bf16x8*)(sQKV + (wv * 16 + nn) * 136 + hh * 32 + quad * 8);
            f32x4 S[4];
            #pragma unroll
            for (int ct = 0; ct < 4; ct++) {
                bf16x8 bk = *(const bf16x8*)(sQKV + (ct * 16 + nn) * 136 + 64 + hh * 32 + quad * 8);
                S[ct] = mfma_bf16(aq, bk, zero4);
            }

            const int i_base = wv * 16 + quad * 4;
            float iq[4];
            #pragma unroll
            for (int r = 0; r < 4; r++) iq[r] = sInv[hh * 64 + i_base + r];

            float rowm[4] = {-3.0e38f, -3.0e38f, -3.0e38f, -3.0e38f};
            #pragma unroll
            for (int ct = 0; ct < 4; ct++) {
                int j = ct * 16 + nn;
                float ivk = sInv[(2 + hh) * 64 + j];
                #pragma unroll
                for (int r = 0; r < 4; r++) {
                    float v = S[ct][r] * iq[r] * ivk * scale + btab[reloff[ct][r] + head];
                    S[ct][r] = v;
                    rowm[r] = fmaxf(rowm[r], v);
                }
            }
            #pragma unroll
            for (int r = 0; r < 4; r++) {
                float m = rowm[r];
                m = fmaxf(m, __shfl_xor(m, 1));
                m = fmaxf(m, __shfl_xor(m, 2));
                m = fmaxf(m, __shfl_xor(m, 4));
                m = fmaxf(m, __shfl_xor(m, 8));
                rowm[r] = m;
            }
            float rsum[4] = {0.f, 0.f, 0.f, 0.f};
            #pragma unroll
            for (int ct = 0; ct < 4; ct++)
                #pragma unroll
                for (int r = 0; r < 4; r++) {
                    float e = __expf(S[ct][r] - rowm[r]);
                    S[ct][r] = e;
                    rsum[r] += e;
                }
            #pragma unroll
            for (int r = 0; r < 4; r++) {
                float s = rsum[r];
                s += __shfl_xor(s, 1);
                s += __shfl_xor(s, 2);
                s += __shfl_xor(s, 4);
                s += __shfl_xor(s, 8);
                rsum[r] = 1.f / s;
            }
            // write P (wave-private rows -> no barrier needed before PV)
            #pragma unroll
            for (int ct = 0; ct < 4; ct++)
                #pragma unroll
                for (int r = 0; r < 4; r++)
                    sP[(i_base + r) * 72 + ct * 16 + nn] = f2bf(S[ct][r] * rsum[r]);

            // ----- O = P V -> sO slice (cols hh*32 + ct2*16 + nn) -----
            bf16x8 ap0 = *(const bf16x8*)(sP + (wv * 16 + nn) * 72 + quad * 8);
            bf16x8 ap1 = *(const bf16x8*)(sP + (wv * 16 + nn) * 72 + 32 + quad * 8);
            #pragma unroll
            for (int ct2 = 0; ct2 < 2; ct2++) {
                bf16x8 bv0 = *(const bf16x8*)(sVt + (hh * 32 + ct2 * 16 + nn) * 72 + quad * 8);
                bf16x8 bv1 = *(const bf16x8*)(sVt + (hh * 32 + ct2 * 16 + nn) * 72 + 32 + quad * 8);
                f32x4 O = mfma_bf16(ap0, bv0, zero4);
                O = mfma_bf16(ap1, bv1, O);
                #pragma unroll
                for (int r = 0; r < 4; r++)
                    sO[(i_base + r) * 72 + hh * 32 + ct2 * 16 + nn] = f2bf(O[r]);
            }
        }
        __syncthreads();   // sO complete (all waves)

        // ===== proj partial GEMM: pacc += sO @ Wp[:, 64p..64p+63]^T =====
        #pragma unroll
        for (int ks2 = 0; ks2 < 2; ks2++) {
            bf16x8 a[4], b[4];
            #pragma unroll
            for (int rt = 0; rt < 4; rt++)
                a[rt] = *(const bf16x8*)(sO + (rt * 16 + nn) * 72 + ks2 * 32 + quad * 8);
            #pragma unroll
            for (int c = 0; c < 4; c++)
                b[c] = *(const bf16x8*)(Wp + (size_t)prow[c] * 256 + p * 64 + ks2 * 32 + quad * 8);
            #pragma unroll
            for (int rt = 0; rt < 4; rt++)
                #pragma unroll
                for (int c = 0; c < 4; c++)
                    pacc[rt][c] = mfma_bf16(a[rt], b[c], pacc[rt][c]);
        }
        __syncthreads();   // protect sQKV/sVt/sO/sInv before next pair
    }

    // ===== output epilogue: pacc + bias + residual -> Xout (roll-back) =====
    #pragma unroll
    for (int c = 0; c < 4; c++) {
        int chan = prow[c];
        float bias = bp[chan];
        #pragma unroll
        for (int rt = 0; rt < 4; rt++)
            #pragma unroll
            for (int r = 0; r < 4; r++) {
                int tok = rt * 16 + quad * 4 + r;
                int h = (wh * 8 + (tok >> 3) + shift) & 63;
                int w = (ww * 8 + (tok & 7) + shift) & 63;
                size_t idx = ((size_t)(bt * 4096 + h * 64 + w)) * 256 + chan;
                Xout[idx] = pacc[rt][c][r] + bias + Xin[idx];
            }
    }
}

// ---------------------------------------------------------------------------
extern "C" void kernel_launch(void* const* d_in, const int* in_sizes, int n_in,
                              void* d_out, int out_size, void* d_ws, size_t ws_size,
                              hipStream_t stream) {
    (void)in_sizes; (void)n_in; (void)out_size; (void)ws_size;

    const float* src        = (const float*)d_in[0];
    const float* a1_qkv_w   = (const float*)d_in[1];
    const float* a1_qkv_b   = (const float*)d_in[2];
    const float* a1_proj_w  = (const float*)d_in[3];
    const float* a1_proj_b  = (const float*)d_in[4];
    const float* a1_ls      = (const float*)d_in[5];
    const float* a1_w1      = (const float*)d_in[6];
    const float* a1_b1      = (const float*)d_in[7];
    const float* a1_w2      = (const float*)d_in[8];
    const float* a2_qkv_w   = (const float*)d_in[9];
    const float* a2_qkv_b   = (const float*)d_in[10];
    const float* a2_proj_w  = (const float*)d_in[11];
    const float* a2_proj_b  = (const float*)d_in[12];
    const float* a2_ls      = (const float*)d_in[13];
    const float* a2_w1      = (const float*)d_in[14];
    const float* a2_b1      = (const float*)d_in[15];
    const float* a2_w2      = (const float*)d_in[16];

    char* ws = (char*)d_ws;
    const size_t SZ_X = 134217728;  // 32*4096*256*4
    float* X0 = (float*)(ws);
    float* X1 = (float*)(ws + SZ_X);
    unsigned short* qw1 = (unsigned short*)(ws + 2 * SZ_X);
    unsigned short* qw2 = qw1 + 196608;
    unsigned short* pw1 = qw2 + 196608;
    unsigned short* pw2 = pw1 + 65536;
    float* bt1 = (float*)(pw2 + 65536);
    float* bt2 = bt1 + 3600;

    k_setup<<<514, 256, 0, stream>>>(a1_qkv_w, a1_proj_w, a2_qkv_w, a2_proj_w,
                                     a1_w1, a1_b1, a1_w2, a2_w1, a2_b1, a2_w2,
                                     qw1, pw1, qw2, pw2, bt1, bt2);
    t_in<<<dim3(32, 8, 32), 256, 0, stream>>>(src, X0);

    // pass 1: no shift, no mask; X0 -> X1
    k_swin<<<2048, 256, 0, stream>>>(X0, qw1, a1_qkv_b, a1_ls, bt1,
                                     pw1, a1_proj_b, X1, 0, 0);
    // pass 2: shift 4, masked; in-place on X1
    k_swin<<<2048, 256, 0, stream>>>(X1, qw2, a2_qkv_b, a2_ls, bt2,
                                     pw2, a2_proj_b, X1, 4, 1);

    t_out<<<dim3(32, 8, 32), 256, 0, stream>>>(X1, (float*)d_out);
}

// Round 7
// 907.501 us; speedup vs baseline: 1.8430x; 1.0039x over previous
//
#include <hip/hip_runtime.h>

// ---------------------------------------------------------------------------
// Two stacked SwinV2 shifted-window attentions, MI355X/gfx950.
// v5 = v4 (incremental proj fusion, no AO round-trip) with:
//  - redundant post-proj barrier deleted (proj(p) + QKV-GEMM(p+1) now one
//    unbarriered MFMA superphase; hazards covered by B1/B2/B3 of p+1)
//  - t_in/t_out: 4x work per block (128x128 tile via four 32-c subtiles,
//    double-buffered LDS), grid 8192 -> 2048, to attack launch latency.
// Pipeline: t_in (NCHW->NHWC f32) -> k_swin x2 (pass2 in-place) -> t_out.
// Mask folded into doubled cpb table (2nd half = bias - 100).
// ---------------------------------------------------------------------------

typedef short bf16x8 __attribute__((ext_vector_type(8)));
typedef float f32x4 __attribute__((ext_vector_type(4)));

__device__ __forceinline__ unsigned short f2bf(float f) {
    union { float f; unsigned int u; } v; v.f = f;
    return (unsigned short)((v.u + 0x7fffu + ((v.u >> 16) & 1u)) >> 16);
}
__device__ __forceinline__ float bf2f(unsigned short b) {
    union { unsigned int u; float f; } v; v.u = ((unsigned int)b) << 16;
    return v.f;
}
__device__ __forceinline__ f32x4 mfma_bf16(bf16x8 a, bf16x8 b, f32x4 c) {
    return __builtin_amdgcn_mfma_f32_16x16x32_bf16(a, b, c, 0, 0, 0);
}

// region id for the swin shifted mask (pH=pW=64, ws=8, shift=4).
__device__ __forceinline__ int region_of(int wh, int ww, int t) {
    int th = t >> 3, tw = t & 7;
    int rh = (wh == 7) ? ((th < 4) ? 1 : 2) : 0;
    int rw = (ww == 7) ? ((tw < 4) ? 1 : 2) : 0;
    return rh * 3 + rw;
}

// ---------------------------------------------------------------------------
// setup: blocks 0..511 convert weights f32->bf16; blocks 512/513 compute the
// cpb tables through 16*sigmoid, duplicated with -100 (mask fold): [2][225][8].
// ---------------------------------------------------------------------------
__global__ __launch_bounds__(256) void k_setup(
    const float* __restrict__ qkvw1, const float* __restrict__ projw1,
    const float* __restrict__ qkvw2, const float* __restrict__ projw2,
    const float* __restrict__ w1a, const float* __restrict__ b1a, const float* __restrict__ w2a,
    const float* __restrict__ w1b, const float* __restrict__ b1b, const float* __restrict__ w2b,
    unsigned short* __restrict__ qw1, unsigned short* __restrict__ pw1,
    unsigned short* __restrict__ qw2, unsigned short* __restrict__ pw2,
    float* __restrict__ bt1, float* __restrict__ bt2)
{
    int b = blockIdx.x, t = threadIdx.x;
    if (b < 512) {
        int idx = b * 256 + t;
        #pragma unroll
        for (int r = 0; r < 4; r++) {
            int i = idx + r * 131072;
            if (i < 196608)        qw1[i]          = f2bf(qkvw1[i]);
            else if (i < 262144)   pw1[i - 196608] = f2bf(projw1[i - 196608]);
            else if (i < 458752)   qw2[i - 262144] = f2bf(qkvw2[i - 262144]);
            else                   pw2[i - 458752] = f2bf(projw2[i - 458752]);
        }
    } else {
        int a = b - 512;
        const float* w1 = a ? w1b : w1a;
        const float* b1 = a ? b1b : b1a;
        const float* w2 = a ? w2b : w2a;
        float* out = a ? bt2 : bt1;
        int k = t;
        if (k >= 225) return;
        int ih = k / 15, iw = k % 15;
        float v0 = (float)(ih - 7) / 7.0f * 8.0f;
        float v1 = (float)(iw - 7) / 7.0f * 8.0f;
        float t0 = (v0 >= 0.f ? 1.f : -1.f) * log2f(fabsf(v0) + 1.f) / 3.0f;
        float t1 = (v1 >= 0.f ? 1.f : -1.f) * log2f(fabsf(v1) + 1.f) / 3.0f;
        float acc[8] = {0.f, 0.f, 0.f, 0.f, 0.f, 0.f, 0.f, 0.f};
        for (int c = 0; c < 512; c++) {
            float hc = t0 * w1[2 * c] + t1 * w1[2 * c + 1] + b1[c];
            hc = fmaxf(hc, 0.f);
            #pragma unroll
            for (int h = 0; h < 8; h++) acc[h] += hc * w2[h * 512 + c];
        }
        #pragma unroll
        for (int h = 0; h < 8; h++) {
            float s = 16.f / (1.f + expf(-acc[h]));
            out[k * 8 + h] = s;                  // unmasked half
            out[1800 + k * 8 + h] = s - 100.f;   // masked half
        }
    }
}

// ---------------------------------------------------------------------------
// transposes: src [32][256][4096] <-> NHWC [32][4096][256].
// 128(hw) x 128(c) per block via four 32-c subtiles, double-buffered LDS,
// float4 on both global sides. grid (32, 2, 32) = 2048 blocks.
// ---------------------------------------------------------------------------
__global__ __launch_bounds__(256) void t_in(const float* __restrict__ src, float* __restrict__ dst) {
    __shared__ float tile[2][32][132];
    int img = blockIdx.z, hw0 = blockIdx.x * 128, c00 = blockIdx.y * 128;
    int tid = threadIdx.x;
    #pragma unroll
    for (int s = 0; s < 4; s++) {
        int c0 = c00 + s * 32;
        float* tb = &tile[s & 1][0][0];
        #pragma unroll
        for (int k = 0; k < 4; k++) {
            int cl = (tid >> 5) + k * 8;
            int hw4 = (tid & 31) * 4;
            float4 v = *(const float4*)(src + ((size_t)img * 256 + c0 + cl) * 4096 + hw0 + hw4);
            *(float4*)(tb + cl * 132 + hw4) = v;
        }
        __syncthreads();
        #pragma unroll
        for (int j = 0; j < 4; j++) {
            int hwl = (tid >> 3) + j * 32;
            int c4 = (tid & 7) * 4;
            float4 o;
            o.x = tb[(c4 + 0) * 132 + hwl]; o.y = tb[(c4 + 1) * 132 + hwl];
            o.z = tb[(c4 + 2) * 132 + hwl]; o.w = tb[(c4 + 3) * 132 + hwl];
            *(float4*)(dst + ((size_t)img * 4096 + hw0 + hwl) * 256 + c0 + c4) = o;
        }
    }
}

__global__ __launch_bounds__(256) void t_out(const float* __restrict__ src, float* __restrict__ dst) {
    __shared__ float tile[2][32][132];
    int img = blockIdx.z, hw0 = blockIdx.x * 128, c00 = blockIdx.y * 128;
    int tid = threadIdx.x;
    #pragma unroll
    for (int s = 0; s < 4; s++) {
        int c0 = c00 + s * 32;
        float* tb = &tile[s & 1][0][0];
        #pragma unroll
        for (int j = 0; j < 4; j++) {
            int hwl = (tid >> 3) + j * 32;
            int c4 = (tid & 7) * 4;
            float4 v = *(const float4*)(src + ((size_t)img * 4096 + hw0 + hwl) * 256 + c0 + c4);
            tb[(c4 + 0) * 132 + hwl] = v.x; tb[(c4 + 1) * 132 + hwl] = v.y;
            tb[(c4 + 2) * 132 + hwl] = v.z; tb[(c4 + 3) * 132 + hwl] = v.w;
        }
        __syncthreads();
        #pragma unroll
        for (int k = 0; k < 4; k++) {
            int cl = (tid >> 5) + k * 8;
            int hw4 = (tid & 31) * 4;
            float4 o;
            o.x = tb[cl * 132 + hw4 + 0]; o.y = tb[cl * 132 + hw4 + 1];
            o.z = tb[cl * 132 + hw4 + 2]; o.w = tb[cl * 132 + hw4 + 3];
            *(float4*)(dst + ((size_t)img * 256 + c0 + cl) * 4096 + hw0 + hw4) = o;
        }
    }
}

// ---------------------------------------------------------------------------
// k_swin: one block per window (2048 blocks, 256 thr = 4 waves, 2 blocks/CU).
// Per head-pair p (x4), 3 barriers:
//   QKV GEMM (A from sX, B=Wq) + epilogue (q/k->sQKV, V->sVt) -> B1 ->
//   norm (sInv) -> B2 -> 2 heads: S=QnKn^T*scale+bias -> softmax -> PV ->
//   sO -> B3 -> proj partial GEMM (pacc += sO @ Wp-slice).
// No barrier after proj: next sO write (PV p+1) is behind B1/B2(p+1); next
// sQKV/sVt writes (epilogue p+1) are ordered vs their readers by B3(p).
// proj(p) and QKV-GEMM(p+1) form one unbarriered MFMA superphase.
// End: out = pacc + bp + residual -> Xout NHWC f32 (roll-back folded).
// ---------------------------------------------------------------------------
__global__ __launch_bounds__(256, 2) void k_swin(
    const float* Xin,                        // NHWC f32 (staging source AND residual)
    const unsigned short* __restrict__ Wq,   // qkv_w bf16 [768][256]
    const float* __restrict__ bq,            // qkv_b f32 [768]
    const float* __restrict__ lsc,           // logit_scale [8]
    const float* __restrict__ btab,          // 16*sigmoid bias [2][225][8]
    const unsigned short* __restrict__ Wp,   // proj_w bf16 [256][256]
    const float* __restrict__ bp,            // proj_b [256]
    float* Xout,                             // output NHWC f32 (== Xin in pass 2)
    int shift, int masked)
{
    __shared__ __align__(16) unsigned short sX[64 * 264];    // X window bf16
    __shared__ __align__(16) unsigned short sQKV[64 * 136];  // q0|q1|k0|k1 (32 chans each)
    __shared__ __align__(16) unsigned short sP[64 * 72];     // softmax probs bf16
    __shared__ __align__(16) unsigned short sVt[64 * 72];    // V transposed [dim][token]
    __shared__ __align__(16) unsigned short sO[64 * 72];     // O-slice [token][64 chans]
    __shared__ float sInv[256];                              // 1/norm: q0,q1,k0,k1

    const int tid = threadIdx.x;
    const int wv = tid >> 6, lane = tid & 63, quad = lane >> 4, nn = lane & 15;
    const int win = blockIdx.x;
    const int bt = win >> 6, wh = (win >> 3) & 7, ww = win & 7;
    const f32x4 zero4 = {0.f, 0.f, 0.f, 0.f};

    // ---- stage X window (shift roll folded into the gather) ----
    {
        int tok = tid >> 2, part = tid & 3;
        int h = (wh * 8 + (tok >> 3) + shift) & 63;
        int w = (ww * 8 + (tok & 7) + shift) & 63;
        const float* srcp = Xin + ((size_t)(bt * 4096 + h * 64 + w)) * 256 + part * 64;
        unsigned short* dstp = sX + tok * 264 + part * 64;
        #pragma unroll
        for (int c = 0; c < 64; c += 8) {
            float4 v0 = *(const float4*)(srcp + c);
            float4 v1 = *(const float4*)(srcp + c + 4);
            uint4 o;
            o.x = (unsigned int)f2bf(v0.x) | ((unsigned int)f2bf(v0.y) << 16);
            o.y = (unsigned int)f2bf(v0.z) | ((unsigned int)f2bf(v0.w) << 16);
            o.z = (unsigned int)f2bf(v1.x) | ((unsigned int)f2bf(v1.y) << 16);
            o.w = (unsigned int)f2bf(v1.z) | ((unsigned int)f2bf(v1.w) << 16);
            *(uint4*)(dstp + c) = o;
        }
    }

    // rel-bias table offsets; mask folded by selecting the -100 table half
    int reloff[4][4];
    #pragma unroll
    for (int ct = 0; ct < 4; ct++) {
        int j = ct * 16 + nn;
        int rj = region_of(wh, ww, j);
        #pragma unroll
        for (int r = 0; r < 4; r++) {
            int i = wv * 16 + quad * 4 + r;
            int rel = ((i >> 3) - (j >> 3) + 7) * 15 + ((i & 7) - (j & 7) + 7);
            bool mk = masked && (region_of(wh, ww, i) != rj);
            reloff[ct][r] = rel * 8 + (mk ? 1800 : 0);
        }
    }

    int prow[4];
    #pragma unroll
    for (int c = 0; c < 4; c++) prow[c] = (wv * 4 + c) * 16 + nn;  // proj output channel

    f32x4 pacc[4][4];   // proj accumulator, persists across head pairs
    #pragma unroll
    for (int rt = 0; rt < 4; rt++)
        #pragma unroll
        for (int c = 0; c < 4; c++) pacc[rt][c] = zero4;

    __syncthreads();

    for (int p = 0; p < 4; p++) {
        // ===== QKV GEMM: 12 wave-disjoint col-tiles (q0 q1 k0 k1 v0 v1) =====
        // (unbarriered continuation of proj(p-1) — one long MFMA superphase)
        f32x4 acc[4][3];
        #pragma unroll
        for (int rt = 0; rt < 4; rt++)
            #pragma unroll
            for (int c = 0; c < 3; c++) acc[rt][c] = zero4;

        int wrow[3], secv[3], colb[3];
        #pragma unroll
        for (int c = 0; c < 3; c++) {
            int ct = wv * 3 + c;           // 12 col-tiles
            int sec = ct >> 1;             // 0..5 : q0 q1 k0 k1 v0 v1
            int kind = sec >> 1;           // 0=q 1=k 2=v
            int head = 2 * p + (sec & 1);
            wrow[c] = kind * 256 + head * 32 + (ct & 1) * 16 + nn;
            secv[c] = sec;
            colb[c] = (sec < 4) ? (sec * 32 + (ct & 1) * 16 + nn)         // sQKV col
                                : ((sec - 4) * 32 + (ct & 1) * 16 + nn);  // sVt chan
        }
        #pragma unroll
        for (int ks = 0; ks < 8; ks++) {
            bf16x8 a[4], b[3];
            #pragma unroll
            for (int rt = 0; rt < 4; rt++)
                a[rt] = *(const bf16x8*)(sX + (rt * 16 + nn) * 264 + ks * 32 + quad * 8);
            #pragma unroll
            for (int c = 0; c < 3; c++)
                b[c] = *(const bf16x8*)(Wq + (size_t)wrow[c] * 256 + ks * 32 + quad * 8);
            #pragma unroll
            for (int rt = 0; rt < 4; rt++)
                #pragma unroll
                for (int c = 0; c < 3; c++)
                    acc[rt][c] = mfma_bf16(a[rt], b[c], acc[rt][c]);
        }

        // ===== epilogue: q/k -> sQKV; v -> sVt (packed transposed) =====
        #pragma unroll
        for (int c = 0; c < 3; c++) {
            int sec = secv[c];
            if (sec < 4) {
                float bias = (sec >= 2) ? 0.f : bq[wrow[c]];  // v2 zeroes key bias
                int col = colb[c];
                #pragma unroll
                for (int rt = 0; rt < 4; rt++)
                    #pragma unroll
                    for (int r = 0; r < 4; r++)
                        sQKV[(rt * 16 + quad * 4 + r) * 136 + col] = f2bf(acc[rt][c][r] + bias);
            } else {
                float bv = bq[wrow[c]];
                int vchan = colb[c];
                #pragma unroll
                for (int rt = 0; rt < 4; rt++) {
                    ushort4 pk;
                    pk.x = f2bf(acc[rt][c][0] + bv);
                    pk.y = f2bf(acc[rt][c][1] + bv);
                    pk.z = f2bf(acc[rt][c][2] + bv);
                    pk.w = f2bf(acc[rt][c][3] + bv);
                    *(ushort4*)(sVt + vchan * 72 + rt * 16 + quad * 4) = pk;
                }
            }
        }
        __syncthreads();   // B1: sQKV/sVt complete

        // ===== norm phase: sInv for q0,q1,k0,k1 (b128 reads) =====
        {
            int t = tid & 63, sec = tid >> 6;
            const unsigned short* row = sQKV + t * 136 + sec * 32;
            float ss = 0.f;
            #pragma unroll
            for (int j = 0; j < 4; j++) {
                bf16x8 v = *(const bf16x8*)(row + j * 8);
                #pragma unroll
                for (int i = 0; i < 8; i++) {
                    float f = bf2f((unsigned short)v[i]);
                    ss += f * f;
                }
            }
            sInv[sec * 64 + t] = 1.f / fmaxf(sqrtf(ss), 1e-12f);
        }
        __syncthreads();   // B2: sInv complete

        #pragma unroll
        for (int hh = 0; hh < 2; hh++) {
            const int head = 2 * p + hh;
            const float scale = __expf(fminf(lsc[head], 4.605170185988092f)); // ln(100)

            // ----- S = Q K^T (wave wv owns rows wv*16..wv*16+15) -----
            bf16x8 aq = *(const bf16x8*)(sQKV + (wv * 16 + nn) * 136 + hh * 32 + quad * 8);
            f32x4 S[4];
            #pragma unroll
            for (int ct = 0; ct < 4; ct++) {
                bf16x8 bk = *(const bf16x8*)(sQKV + (ct * 16 + nn) * 136 + 64 + hh * 32 + quad * 8);
                S[ct] = mfma_bf16(aq, bk, zero4);
            }

            const int i_base = wv * 16 + quad * 4;
            float iq[4];
            #pragma unroll
            for (int r = 0; r < 4; r++) iq[r] = sInv[hh * 64 + i_base + r];

            float rowm[4] = {-3.0e38f, -3.0e38f, -3.0e38f, -3.0e38f};
            #pragma unroll
            for (int ct = 0; ct < 4; ct++) {
                int j = ct * 16 + nn;
                float ivk = sInv[(2 + hh) * 64 + j];
                #pragma unroll
                for (int r = 0; r < 4; r++) {
                    float v = S[ct][r] * iq[r] * ivk * scale + btab[reloff[ct][r] + head];
                    S[ct][r] = v;
                    rowm[r] = fmaxf(rowm[r], v);
                }
            }
            #pragma unroll
            for (int r = 0; r < 4; r++) {
                float m = rowm[r];
                m = fmaxf(m, __shfl_xor(m, 1));
                m = fmaxf(m, __shfl_xor(m, 2));
                m = fmaxf(m, __shfl_xor(m, 4));
                m = fmaxf(m, __shfl_xor(m, 8));
                rowm[r] = m;
            }
            float rsum[4] = {0.f, 0.f, 0.f, 0.f};
            #pragma unroll
            for (int ct = 0; ct < 4; ct++)
                #pragma unroll
                for (int r = 0; r < 4; r++) {
                    float e = __expf(S[ct][r] - rowm[r]);
                    S[ct][r] = e;
                    rsum[r] += e;
                }
            #pragma unroll
            for (int r = 0; r < 4; r++) {
                float s = rsum[r];
                s += __shfl_xor(s, 1);
                s += __shfl_xor(s, 2);
                s += __shfl_xor(s, 4);
                s += __shfl_xor(s, 8);
                rsum[r] = 1.f / s;
            }
            // write P (wave-private rows -> no barrier needed before PV)
            #pragma unroll
            for (int ct = 0; ct < 4; ct++)
                #pragma unroll
                for (int r = 0; r < 4; r++)
                    sP[(i_base + r) * 72 + ct * 16 + nn] = f2bf(S[ct][r] * rsum[r]);

            // ----- O = P V -> sO slice (cols hh*32 + ct2*16 + nn) -----
            bf16x8 ap0 = *(const bf16x8*)(sP + (wv * 16 + nn) * 72 + quad * 8);
            bf16x8 ap1 = *(const bf16x8*)(sP + (wv * 16 + nn) * 72 + 32 + quad * 8);
            #pragma unroll
            for (int ct2 = 0; ct2 < 2; ct2++) {
                bf16x8 bv0 = *(const bf16x8*)(sVt + (hh * 32 + ct2 * 16 + nn) * 72 + quad * 8);
                bf16x8 bv1 = *(const bf16x8*)(sVt + (hh * 32 + ct2 * 16 + nn) * 72 + 32 + quad * 8);
                f32x4 O = mfma_bf16(ap0, bv0, zero4);
                O = mfma_bf16(ap1, bv1, O);
                #pragma unroll
                for (int r = 0; r < 4; r++)
                    sO[(i_base + r) * 72 + hh * 32 + ct2 * 16 + nn] = f2bf(O[r]);
            }
        }
        __syncthreads();   // B3: sO complete (all waves)

        // ===== proj partial GEMM: pacc += sO @ Wp[:, 64p..64p+63]^T =====
        #pragma unroll
        for (int ks2 = 0; ks2 < 2; ks2++) {
            bf16x8 a[4], b[4];
            #pragma unroll
            for (int rt = 0; rt < 4; rt++)
                a[rt] = *(const bf16x8*)(sO + (rt * 16 + nn) * 72 + ks2 * 32 + quad * 8);
            #pragma unroll
            for (int c = 0; c < 4; c++)
                b[c] = *(const bf16x8*)(Wp + (size_t)prow[c] * 256 + p * 64 + ks2 * 32 + quad * 8);
            #pragma unroll
            for (int rt = 0; rt < 4; rt++)
                #pragma unroll
                for (int c = 0; c < 4; c++)
                    pacc[rt][c] = mfma_bf16(a[rt], b[c], pacc[rt][c]);
        }
        // NO barrier here: next sO write (PV of p+1) is behind B1+B2 of p+1;
        // next sQKV/sVt writes (epilogue p+1) are ordered vs readers by B3.
    }

    // ===== output epilogue: pacc + bias + residual -> Xout (roll-back) =====
    #pragma unroll
    for (int c = 0; c < 4; c++) {
        int chan = prow[c];
        float bias = bp[chan];
        #pragma unroll
        for (int rt = 0; rt < 4; rt++)
            #pragma unroll
            for (int r = 0; r < 4; r++) {
                int tok = rt * 16 + quad * 4 + r;
                int h = (wh * 8 + (tok >> 3) + shift) & 63;
                int w = (ww * 8 + (tok & 7) + shift) & 63;
                size_t idx = ((size_t)(bt * 4096 + h * 64 + w)) * 256 + chan;
                Xout[idx] = pacc[rt][c][r] + bias + Xin[idx];
            }
    }
}

// ---------------------------------------------------------------------------
extern "C" void kernel_launch(void* const* d_in, const int* in_sizes, int n_in,
                              void* d_out, int out_size, void* d_ws, size_t ws_size,
                              hipStream_t stream) {
    (void)in_sizes; (void)n_in; (void)out_size; (void)ws_size;

    const float* src        = (const float*)d_in[0];
    const float* a1_qkv_w   = (const float*)d_in[1];
    const float* a1_qkv_b   = (const float*)d_in[2];
    const float* a1_proj_w  = (const float*)d_in[3];
    const float* a1_proj_b  = (const float*)d_in[4];
    const float* a1_ls      = (const float*)d_in[5];
    const float* a1_w1      = (const float*)d_in[6];
    const float* a1_b1      = (const float*)d_in[7];
    const float* a1_w2      = (const float*)d_in[8];
    const float* a2_qkv_w   = (const float*)d_in[9];
    const float* a2_qkv_b   = (const float*)d_in[10];
    const float* a2_proj_w  = (const float*)d_in[11];
    const float* a2_proj_b  = (const float*)d_in[12];
    const float* a2_ls      = (const float*)d_in[13];
    const float* a2_w1      = (const float*)d_in[14];
    const float* a2_b1      = (const float*)d_in[15];
    const float* a2_w2      = (const float*)d_in[16];

    char* ws = (char*)d_ws;
    const size_t SZ_X = 134217728;  // 32*4096*256*4
    float* X0 = (float*)(ws);
    float* X1 = (float*)(ws + SZ_X);
    unsigned short* qw1 = (unsigned short*)(ws + 2 * SZ_X);
    unsigned short* qw2 = qw1 + 196608;
    unsigned short* pw1 = qw2 + 196608;
    unsigned short* pw2 = pw1 + 65536;
    float* bt1 = (float*)(pw2 + 65536);
    float* bt2 = bt1 + 3600;

    k_setup<<<514, 256, 0, stream>>>(a1_qkv_w, a1_proj_w, a2_qkv_w, a2_proj_w,
                                     a1_w1, a1_b1, a1_w2, a2_w1, a2_b1, a2_w2,
                                     qw1, pw1, qw2, pw2, bt1, bt2);
    t_in<<<dim3(32, 2, 32), 256, 0, stream>>>(src, X0);

    // pass 1: no shift, no mask; X0 -> X1
    k_swin<<<2048, 256, 0, stream>>>(X0, qw1, a1_qkv_b, a1_ls, bt1,
                                     pw1, a1_proj_b, X1, 0, 0);
    // pass 2: shift 4, masked; in-place on X1
    k_swin<<<2048, 256, 0, stream>>>(X1, qw2, a2_qkv_b, a2_ls, bt2,
                                     pw2, a2_proj_b, X1, 4, 1);

    t_out<<<dim3(32, 2, 32), 256, 0, stream>>>(X1, (float*)d_out);
}